// Round 13
// baseline (959.732 us; speedup 1.0000x reference)
//
#include <hip/hip_runtime.h>
#include <math.h>

#define N_NODES 50000
#define E_EDGES 1600000
#define D_IN 128
#define H_DIM 64
#define R_REL 3
#define ETOT (E_EDGES + N_NODES)
#define NEG_SLOPE 0.2f

// radix-partition CSR build parameters
#define BSHIFT 7
#define BSIZE 128                              // dst nodes per bucket
#define NBUCK ((N_NODES + BSIZE - 1) / BSIZE)  // 391
#define CHUNK 7168                             // edges per block in passes A/B (56KB stage)
#define NBLK ((ETOT + CHUNK - 1) / CHUNK)      // 231
#define CCAP 5120                              // partC LDS stage capacity (40KB)

typedef int i32x2 __attribute__((ext_vector_type(2)));
typedef float f32x4 __attribute__((ext_vector_type(4)));

// ---------------- thread-tiled LDS GEMM + attention coefficients ----------------
// Block: 256 threads -> 128 nodes x 64 cols. Thread (tn 0..15, tc 0..15) computes
// an 8-row x 4-col micro-tile. Per k4: 12 ds_read_b128 for 128 FMAs.
// Scalarized accumulators; one av row live at a time (avoid round-10 spill).
template <int DIN>
__global__ __launch_bounds__(256) void gemm_alpha_kernel(
    const float* __restrict__ xin, size_t xin_rstride,
    const float* __restrict__ W, size_t W_rstride,
    const float* __restrict__ a_s, const float* __restrict__ a_d, size_t a_rstride,
    float* __restrict__ h, size_t h_rstride,
    float* __restrict__ as_out, float* __restrict__ ad_out, size_t v_rstride,
    int r0)
{
    int rr = blockIdx.y;
    int rW = r0 + rr;
    xin += (size_t)rr * xin_rstride;
    W += (size_t)rW * W_rstride;
    a_s += (size_t)rW * a_rstride;
    a_d += (size_t)rW * a_rstride;
    h += (size_t)rr * h_rstride;
    as_out += (size_t)rr * v_rstride;
    ad_out += (size_t)rr * v_rstride;

    constexpr int KC = 64;
    constexpr int XSTR = KC + 4;   // 68
    __shared__ __align__(16) float xls[128 * XSTR];  // 34.8 KB
    __shared__ __align__(16) float wls[KC * 64];     // 16 KB
    int t = threadIdx.x;
    int n0 = blockIdx.x * 128;
    int nrows = N_NODES - n0; if (nrows > 128) nrows = 128;
    int tn = t >> 4;   // 0..15 -> rows tn*8..+8
    int tc = t & 15;   // 0..15 -> cols tc*4..+4

    float4 acc0 = {0,0,0,0}, acc1 = acc0, acc2 = acc0, acc3 = acc0;
    float4 acc4 = acc0, acc5 = acc0, acc6 = acc0, acc7 = acc0;

    for (int kc = 0; kc < DIN; kc += KC) {
        if (kc) __syncthreads();
        int nf4 = nrows * 16;
        for (int f = t; f < nf4; f += 256) {
            int row = f >> 4;
            int q = f & 15;
            float4 xv = *reinterpret_cast<const float4*>(
                xin + (size_t)(n0 + row) * DIN + kc + q * 4);
            *reinterpret_cast<float4*>(&xls[row * XSTR + q * 4]) = xv;
        }
        for (int f = t; f < KC * 16; f += 256) {
            int kk = f >> 4;
            int q = f & 15;
            *reinterpret_cast<float4*>(&wls[kk * 64 + q * 4]) =
                *reinterpret_cast<const float4*>(W + (size_t)(kc + kk) * 64 + q * 4);
        }
        __syncthreads();

#pragma unroll
        for (int k4 = 0; k4 < KC / 4; ++k4) {
            float4 bv0 = *reinterpret_cast<const float4*>(
                &wls[(k4 * 4 + 0) * 64 + tc * 4]);
            float4 bv1 = *reinterpret_cast<const float4*>(
                &wls[(k4 * 4 + 1) * 64 + tc * 4]);
            float4 bv2 = *reinterpret_cast<const float4*>(
                &wls[(k4 * 4 + 2) * 64 + tc * 4]);
            float4 bv3 = *reinterpret_cast<const float4*>(
                &wls[(k4 * 4 + 3) * 64 + tc * 4]);
#define GEMM_ROW(I, ACC)                                                    \
            {                                                               \
                float4 av = *reinterpret_cast<const float4*>(               \
                    &xls[(tn * 8 + (I)) * XSTR + k4 * 4]);                  \
                ACC.x = fmaf(av.x, bv0.x, ACC.x);                           \
                ACC.y = fmaf(av.x, bv0.y, ACC.y);                           \
                ACC.z = fmaf(av.x, bv0.z, ACC.z);                           \
                ACC.w = fmaf(av.x, bv0.w, ACC.w);                           \
                ACC.x = fmaf(av.y, bv1.x, ACC.x);                           \
                ACC.y = fmaf(av.y, bv1.y, ACC.y);                           \
                ACC.z = fmaf(av.y, bv1.z, ACC.z);                           \
                ACC.w = fmaf(av.y, bv1.w, ACC.w);                           \
                ACC.x = fmaf(av.z, bv2.x, ACC.x);                           \
                ACC.y = fmaf(av.z, bv2.y, ACC.y);                           \
                ACC.z = fmaf(av.z, bv2.z, ACC.z);                           \
                ACC.w = fmaf(av.z, bv2.w, ACC.w);                           \
                ACC.x = fmaf(av.w, bv3.x, ACC.x);                           \
                ACC.y = fmaf(av.w, bv3.y, ACC.y);                           \
                ACC.z = fmaf(av.w, bv3.z, ACC.z);                           \
                ACC.w = fmaf(av.w, bv3.w, ACC.w);                           \
            }
            GEMM_ROW(0, acc0)
            GEMM_ROW(1, acc1)
            GEMM_ROW(2, acc2)
            GEMM_ROW(3, acc3)
            GEMM_ROW(4, acc4)
            GEMM_ROW(5, acc5)
            GEMM_ROW(6, acc6)
            GEMM_ROW(7, acc7)
#undef GEMM_ROW
        }
    }

    float4 asj = *reinterpret_cast<const float4*>(a_s + tc * 4);
    float4 adj = *reinterpret_cast<const float4*>(a_d + tc * 4);
#define GEMM_EPI(I, ACC)                                                    \
    {                                                                       \
        int node = n0 + tn * 8 + (I);                                       \
        bool ok = node < N_NODES;                                           \
        if (ok)                                                             \
            *reinterpret_cast<float4*>(h + (size_t)node * 64 + tc * 4) = ACC; \
        float vs = ACC.x * asj.x + ACC.y * asj.y + ACC.z * asj.z + ACC.w * asj.w; \
        float vd = ACC.x * adj.x + ACC.y * adj.y + ACC.z * adj.z + ACC.w * adj.w; \
        vs += __shfl_xor(vs, 8, 64); vd += __shfl_xor(vd, 8, 64);           \
        vs += __shfl_xor(vs, 4, 64); vd += __shfl_xor(vd, 4, 64);           \
        vs += __shfl_xor(vs, 2, 64); vd += __shfl_xor(vd, 2, 64);           \
        vs += __shfl_xor(vs, 1, 64); vd += __shfl_xor(vd, 1, 64);           \
        if (ok && tc == 0) { as_out[node] = vs; ad_out[node] = vd; }        \
    }
    GEMM_EPI(0, acc0)
    GEMM_EPI(1, acc1)
    GEMM_EPI(2, acc2)
    GEMM_EPI(3, acc3)
    GEMM_EPI(4, acc4)
    GEMM_EPI(5, acc5)
    GEMM_EPI(6, acc6)
    GEMM_EPI(7, acc7)
#undef GEMM_EPI
}

// ---------------- radix-partitioned CSR build (batched over relations) ----------------
// Pass A: per-block LDS histogram over NBUCK dst-buckets. bh layout: [r][blk][bucket]
__global__ __launch_bounds__(256) void partA_hist(const int* __restrict__ edge_index,
                                                  int* __restrict__ bh)
{
    __shared__ int hist[NBUCK];
    int t = threadIdx.x;
    int r = blockIdx.x / NBLK;
    int blk = blockIdx.x % NBLK;
    const int* dstE = edge_index + (size_t)r * 2 * E_EDGES + E_EDGES;
    for (int b = t; b < NBUCK; b += 256) hist[b] = 0;
    __syncthreads();
    int base = blk * CHUNK;
#pragma unroll 4
    for (int u = 0; u < CHUNK / 256; ++u) {
        int i = base + u * 256 + t;
        if (i < ETOT) {
            int d = (i < E_EDGES) ? dstE[i] : (i - E_EDGES);
            atomicAdd(&hist[d >> BSHIFT], 1);
        }
    }
    __syncthreads();
    int* bh_blk = bh + ((size_t)r * NBLK + blk) * NBUCK;
    for (int b = t; b < NBUCK; b += 256) bh_blk[b] = hist[b];
}

// Pass A2: per (r,bucket), exclusive scan of per-block counts -> bhoff + total.
__global__ __launch_bounds__(256) void partA2_scan(const int* __restrict__ bh,
                                                   int* __restrict__ bhoff,
                                                   int* __restrict__ btot)
{
    __shared__ int tmp[256];
    int r = blockIdx.x / NBUCK;
    int b = blockIdx.x % NBUCK;
    int t = threadIdx.x;
    const int* bh_r = bh + (size_t)r * NBLK * NBUCK;
    int* bhoff_r = bhoff + (size_t)r * NBLK * NBUCK;
    int v = (t < NBLK) ? bh_r[(size_t)t * NBUCK + b] : 0;   // NBLK=231 <= 256
    int x = v;
#pragma unroll
    for (int off = 1; off < 256; off <<= 1) {
        tmp[t] = x;
        __syncthreads();
        int a = (t >= off) ? tmp[t - off] : 0;
        __syncthreads();
        x += a;
    }
    if (t < NBLK) bhoff_r[(size_t)t * NBUCK + b] = x - v;
    if (t == 255) btot[r * NBUCK + b] = x;
}

// Pass A3: per relation, exclusive scan of bucket totals -> bucket bases.
__global__ __launch_bounds__(256) void partA3_scan(const int* __restrict__ btot,
                                                   int* __restrict__ bbase)
{
    __shared__ int tmp[256];
    __shared__ int carry_s;
    int r = blockIdx.x;
    int t = threadIdx.x;
    const int* row = btot + r * NBUCK;
    int* outb = bbase + r * (NBUCK + 1);
    if (t == 0) carry_s = 0;
    __syncthreads();
    for (int base = 0; base < NBUCK; base += 256) {
        int idx = base + t;
        int v = (idx < NBUCK) ? row[idx] : 0;
        int x = v;
#pragma unroll
        for (int off = 1; off < 256; off <<= 1) {
            tmp[t] = x;
            __syncthreads();
            int a = (t >= off) ? tmp[t - off] : 0;
            __syncthreads();
            x += a;
        }
        int carry = carry_s;
        if (idx < NBUCK) outb[idx] = carry + x - v;
        __syncthreads();
        if (t == 255) carry_s = carry + x;
        __syncthreads();
    }
    if (t == 0) outb[NBUCK] = carry_s;  // == ETOT
}

// Pass B: block-local LDS counting sort by bucket, then LINEAR coalesced write-out.
// Record: .x = src | (dst << 16) (both < 2^16), .y = w bits.
__global__ __launch_bounds__(256) void partB_scatter(
    const int* __restrict__ edge_index, const float* __restrict__ edge_weight,
    const int* __restrict__ bh, const int* __restrict__ bhoff,
    const int* __restrict__ bbase, int2* __restrict__ sedge)
{
    __shared__ int2 stage[CHUNK];     // 56 KB
    __shared__ int cur[NBUCK];
    __shared__ int gbase[NBUCK];
    __shared__ int tmp[256];
    __shared__ int carry_s;
    int t = threadIdx.x;
    int r = blockIdx.x / NBLK;
    int blk = blockIdx.x % NBLK;
    const int* srcE = edge_index + (size_t)r * 2 * E_EDGES;
    const int* dstE = srcE + E_EDGES;
    const float* ewr = edge_weight + (size_t)r * E_EDGES;
    const int* bh_blk = bh + ((size_t)r * NBLK + blk) * NBUCK;
    const int* bhoff_blk = bhoff + ((size_t)r * NBLK + blk) * NBUCK;
    const int* bbase_r = bbase + r * (NBUCK + 1);
    int2* se_r = sedge + (size_t)r * ETOT;

    if (t == 0) carry_s = 0;
    __syncthreads();
    for (int base = 0; base < NBUCK; base += 256) {
        int idx = base + t;
        int v = (idx < NBUCK) ? bh_blk[idx] : 0;
        int x = v;
#pragma unroll
        for (int off = 1; off < 256; off <<= 1) {
            tmp[t] = x;
            __syncthreads();
            int a = (t >= off) ? tmp[t - off] : 0;
            __syncthreads();
            x += a;
        }
        int carry = carry_s;
        if (idx < NBUCK) {
            int ls = carry + x - v;
            cur[idx] = ls;
            gbase[idx] = bbase_r[idx] + bhoff_blk[idx] - ls;
        }
        __syncthreads();
        if (t == 255) carry_s = carry + x;
        __syncthreads();
    }

    int base0 = blk * CHUNK;
    int chunkLen = ETOT - base0; if (chunkLen > CHUNK) chunkLen = CHUNK;
#pragma unroll 4
    for (int u = 0; u < CHUNK / 256; ++u) {
        int i = base0 + u * 256 + t;
        if (i < ETOT) {
            int s, d;
            float w;
            if (i < E_EDGES) {
                s = srcE[i]; d = dstE[i]; w = ewr[i];
            } else {
                s = d = i - E_EDGES; w = 1.0f;
            }
            int pos = atomicAdd(&cur[d >> BSHIFT], 1);  // LDS atomic
            int2 pay;
            pay.x = s | (d << 16);
            pay.y = __float_as_int(w);
            stage[pos] = pay;
        }
    }
    __syncthreads();
    for (int j = t; j < chunkLen; j += 256) {
        int2 rec = stage[j];
        int d = (int)(((unsigned)rec.x) >> 16);
        se_r[gbase[d >> BSHIFT] + j] = rec;
    }
}

// Pass C: per-bucket LDS-staged counting sort, IN PLACE in sedge -> rs + final {src,w}.
__global__ __launch_bounds__(256) void partC_sort(
    const int* __restrict__ bbase, int2* __restrict__ sedge,
    int* __restrict__ rs)
{
    __shared__ int2 stage[CCAP];   // 40 KB
    __shared__ int cnt[BSIZE];
    __shared__ int rsl[BSIZE];
    __shared__ int tmp[BSIZE];
    __shared__ int cur[BSIZE];
    int r = blockIdx.x / NBUCK;
    int b = blockIdx.x % NBUCK;
    int t = threadIdx.x;
    const int* bbase_r = bbase + r * (NBUCK + 1);
    int* rs_r = rs + r * (N_NODES + 1);
    int2* se_r = sedge + (size_t)r * ETOT;
    int lo = b * BSIZE;
    int nn = N_NODES - lo; if (nn > BSIZE) nn = BSIZE;
    int seg0 = bbase_r[b], seg1 = bbase_r[b + 1];
    int len = seg1 - seg0;
    if (t < BSIZE) { cnt[t] = 0; cur[t] = 0; }
    __syncthreads();
    for (int k = t; k < len; k += 256) {
        int2 pw = se_r[seg0 + k];   // coalesced read
        if (k < CCAP) stage[k] = pw;
        atomicAdd(&cnt[(pw.x >> 16) & (BSIZE - 1)], 1);
    }
    __syncthreads();
    int v = 0, x = 0;
    if (t < BSIZE) { v = cnt[t]; x = v; }
#pragma unroll
    for (int off = 1; off < BSIZE; off <<= 1) {
        if (t < BSIZE) tmp[t] = x;
        __syncthreads();
        int a = (t < BSIZE && t >= off) ? tmp[t - off] : 0;
        __syncthreads();
        x += a;
    }
    if (t < BSIZE) rsl[t] = x - v;  // local exclusive
    __syncthreads();
    if (t < nn) rs_r[lo + t] = seg0 + rsl[t];
    if (b == NBUCK - 1 && t == 0) rs_r[N_NODES] = seg1;
    for (int k = t; k < len; k += 256) {
        int2 pw = (k < CCAP) ? stage[k] : se_r[seg0 + k];
        int dlo = (pw.x >> 16) & (BSIZE - 1);
        int pos = rsl[dlo] + atomicAdd(&cur[dlo], 1);
        int2 rec;
        rec.x = pw.x & 0xFFFF;
        rec.y = pw.y;
        se_r[seg0 + pos] = rec;
    }
}

// ---------------- per-node softmax + aggregation (no max pass) ----------------
// One wave per dst node; blockIdx.y = relation. The <=64-edge chunk's gather is
// fully unrolled into 3 register groups + reuse: all (up to 12) float4 gathers
// issue BEFORE any FMA. Branches on rem are wave-uniform (free). Out-of-range
// shfl slots carry pq=0 (their h loads hit h[0], L1-hot, harmless).
__global__ __launch_bounds__(256) void agg_kernel(
    const int* __restrict__ rs, const int2* __restrict__ sedge,
    const float* __restrict__ as_v, const float* __restrict__ ad_v, size_t v_rstride,
    const float* __restrict__ h, size_t h_rstride,
    const float* __restrict__ bias, size_t b_rstride,
    float* __restrict__ out, size_t out_roffset, int out_stride, int do_relu,
    int r0)
{
    int rr = blockIdx.y;
    int rW = r0 + rr;
    rs += (size_t)rW * (N_NODES + 1);
    sedge += (size_t)rW * ETOT;
    as_v += (size_t)rr * v_rstride;
    ad_v += (size_t)rr * v_rstride;
    h += (size_t)rr * h_rstride;
    bias += (size_t)rW * b_rstride;
    out += (size_t)rr * out_roffset;

    int wave = (int)(((size_t)blockIdx.x * blockDim.x + threadIdx.x) >> 6);
    int lane = threadIdx.x & 63;
    if (wave >= N_NODES) return;
    int beg = rs[wave], end = rs[wave + 1];
    float ad_n = ad_v[wave];

    int sub = lane >> 4;   // edge sub-slot 0..3
    int f = lane & 15;     // feature quad index
    const float* hf = h + f * 4;

    float ssum = 0.f;
    float4 a0 = {0.f, 0.f, 0.f, 0.f};
    float4 a1 = a0, a2 = a0, a3 = a0;

// macros take explicit variable names (no token pasting: `X0.x` after `##`
// lexes as an invalid pp-number)
#define GLOAD(T0, S0, Q0, H0, S1, Q1, H1, S2, Q2, H2, S3, Q3, H3)             \
    S0 = __shfl(srcv, (T0) + sub, 64);                                        \
    Q0 = __shfl(pq, (T0) + sub, 64);                                          \
    S1 = __shfl(srcv, (T0) + 4 + sub, 64);                                    \
    Q1 = __shfl(pq, (T0) + 4 + sub, 64);                                      \
    S2 = __shfl(srcv, (T0) + 8 + sub, 64);                                    \
    Q2 = __shfl(pq, (T0) + 8 + sub, 64);                                      \
    S3 = __shfl(srcv, (T0) + 12 + sub, 64);                                   \
    Q3 = __shfl(pq, (T0) + 12 + sub, 64);                                     \
    H0 = *reinterpret_cast<const float4*>(hf + (size_t)S0 * 64);              \
    H1 = *reinterpret_cast<const float4*>(hf + (size_t)S1 * 64);              \
    H2 = *reinterpret_cast<const float4*>(hf + (size_t)S2 * 64);              \
    H3 = *reinterpret_cast<const float4*>(hf + (size_t)S3 * 64);

#define GFMA(Q0, H0, Q1, H1, Q2, H2, Q3, H3)                                  \
    a0.x = fmaf(Q0, H0.x, a0.x);                                              \
    a0.y = fmaf(Q0, H0.y, a0.y);                                              \
    a0.z = fmaf(Q0, H0.z, a0.z);                                              \
    a0.w = fmaf(Q0, H0.w, a0.w);                                              \
    a1.x = fmaf(Q1, H1.x, a1.x);                                              \
    a1.y = fmaf(Q1, H1.y, a1.y);                                              \
    a1.z = fmaf(Q1, H1.z, a1.z);                                              \
    a1.w = fmaf(Q1, H1.w, a1.w);                                              \
    a2.x = fmaf(Q2, H2.x, a2.x);                                              \
    a2.y = fmaf(Q2, H2.y, a2.y);                                              \
    a2.z = fmaf(Q2, H2.z, a2.z);                                              \
    a2.w = fmaf(Q2, H2.w, a2.w);                                              \
    a3.x = fmaf(Q3, H3.x, a3.x);                                              \
    a3.y = fmaf(Q3, H3.y, a3.y);                                              \
    a3.z = fmaf(Q3, H3.z, a3.z);                                              \
    a3.w = fmaf(Q3, H3.w, a3.w);

    for (int cbeg = beg; cbeg < end; cbeg += 64) {
        int rem = end - cbeg;
        if (rem > 64) rem = 64;
        int srcv = 0;
        float pq = 0.f;
        if (lane < rem) {
            i32x2 pe = __builtin_nontemporal_load(
                reinterpret_cast<const i32x2*>(sedge + cbeg + lane));
            srcv = pe.x;
            float e = as_v[srcv] + ad_n;
            e = (e > 0.f) ? e : NEG_SLOPE * e;
            float p = __expf(e);
            ssum += p;
            pq = p * __int_as_float(pe.y);
        }
        bool gB = rem > 16, gC = rem > 32, gD = rem > 48;
        int sA0, sA1, sA2, sA3, sB0 = 0, sB1 = 0, sB2 = 0, sB3 = 0;
        int sC0 = 0, sC1 = 0, sC2 = 0, sC3 = 0;
        float qA0, qA1, qA2, qA3, qB0 = 0.f, qB1 = 0.f, qB2 = 0.f, qB3 = 0.f;
        float qC0 = 0.f, qC1 = 0.f, qC2 = 0.f, qC3 = 0.f;
        float4 hA0, hA1, hA2, hA3, hB0, hB1, hB2, hB3, hC0, hC1, hC2, hC3;
        GLOAD(0, sA0, qA0, hA0, sA1, qA1, hA1, sA2, qA2, hA2, sA3, qA3, hA3)
        if (gB) { GLOAD(16, sB0, qB0, hB0, sB1, qB1, hB1, sB2, qB2, hB2, sB3, qB3, hB3) }
        if (gC) { GLOAD(32, sC0, qC0, hC0, sC1, qC1, hC1, sC2, qC2, hC2, sC3, qC3, hC3) }
        GFMA(qA0, hA0, qA1, hA1, qA2, hA2, qA3, hA3)
        if (gD) {  // reuse group-A registers for slots 48-63
            GLOAD(48, sA0, qA0, hA0, sA1, qA1, hA1, sA2, qA2, hA2, sA3, qA3, hA3)
        }
        if (gB) { GFMA(qB0, hB0, qB1, hB1, qB2, hB2, qB3, hB3) }
        if (gC) { GFMA(qC0, hC0, qC1, hC1, qC2, hC2, qC3, hC3) }
        if (gD) { GFMA(qA0, hA0, qA1, hA1, qA2, hA2, qA3, hA3) }
    }
#undef GLOAD
#undef GFMA

#pragma unroll
    for (int off = 32; off > 0; off >>= 1) ssum += __shfl_xor(ssum, off, 64);
    a0.x = (a0.x + a1.x) + (a2.x + a3.x);
    a0.y = (a0.y + a1.y) + (a2.y + a3.y);
    a0.z = (a0.z + a1.z) + (a2.z + a3.z);
    a0.w = (a0.w + a1.w) + (a2.w + a3.w);
    a0.x += __shfl_xor(a0.x, 16, 64);
    a0.y += __shfl_xor(a0.y, 16, 64);
    a0.z += __shfl_xor(a0.z, 16, 64);
    a0.w += __shfl_xor(a0.w, 16, 64);
    a0.x += __shfl_xor(a0.x, 32, 64);
    a0.y += __shfl_xor(a0.y, 32, 64);
    a0.z += __shfl_xor(a0.z, 32, 64);
    a0.w += __shfl_xor(a0.w, 32, 64);

    if (sub == 0) {
        float inv = 1.f / (ssum + 1e-16f);
        const float4 bv = *reinterpret_cast<const float4*>(bias + f * 4);
        float4 o;
        o.x = fmaf(a0.x, inv, bv.x);
        o.y = fmaf(a0.y, inv, bv.y);
        o.z = fmaf(a0.z, inv, bv.z);
        o.w = fmaf(a0.w, inv, bv.w);
        float* dst = out + (size_t)wave * out_stride + f * 4;
        if (do_relu) {
            o.x = fmaxf(o.x, 0.f);
            o.y = fmaxf(o.y, 0.f);
            o.z = fmaxf(o.z, 0.f);
            o.w = fmaxf(o.w, 0.f);
            *reinterpret_cast<float4*>(dst) = o;   // xbuf: re-read by next gemm
        } else {
            f32x4 o4 = {o.x, o.y, o.z, o.w};       // final out: never re-read
            __builtin_nontemporal_store(o4, reinterpret_cast<f32x4*>(dst));
        }
    }
}

extern "C" void kernel_launch(void* const* d_in, const int* in_sizes, int n_in,
                              void* d_out, int out_size, void* d_ws, size_t ws_size,
                              hipStream_t stream)
{
    (void)in_sizes; (void)n_in; (void)out_size;
    const float* x = (const float*)d_in[0];
    const float* edge_weight = (const float*)d_in[1];
    const float* W0 = (const float*)d_in[2];
    const float* W1 = (const float*)d_in[3];
    const float* W2 = (const float*)d_in[4];
    const float* a_src = (const float*)d_in[5];
    const float* a_dst = (const float*)d_in[6];
    const float* bias = (const float*)d_in[7];
    const int* edge_index = (const int*)d_in[8];
    float* out = (float*)d_out;

    char* ws = (char*)d_ws;
    size_t off = 0;
    auto alloc = [&](size_t bytes) {
        void* p = ws + off;
        off += (bytes + 255) & ~(size_t)255;
        return p;
    };
    int2* sedge = (int2*)alloc((size_t)R_REL * ETOT * 8);        // 39.6 MB
    int* bh = (int*)alloc((size_t)R_REL * NBLK * NBUCK * 4);     // 1.08 MB
    int* bhoff = (int*)alloc((size_t)R_REL * NBLK * NBUCK * 4);  // 1.08 MB
    int* btot = (int*)alloc((size_t)R_REL * NBUCK * 4);
    int* bbase = (int*)alloc((size_t)R_REL * (NBUCK + 1) * 4);
    int* rs = (int*)alloc((size_t)R_REL * (N_NODES + 1) * 4);

    // batched path needs 3x node buffers (~78 MB extra); fall back if ws too small
    size_t per_rel = ((size_t)N_NODES * 64 * 4 * 2 + (size_t)N_NODES * 4 * 2 + 1024);
    int K = (ws_size >= off + 3 * per_rel + (1 << 20)) ? 3 : 1;
    float* hbuf = (float*)alloc((size_t)K * N_NODES * 64 * 4);
    float* xbuf = (float*)alloc((size_t)K * N_NODES * 64 * 4);
    float* asv = (float*)alloc((size_t)K * N_NODES * 4);
    float* adv = (float*)alloc((size_t)K * N_NODES * 4);

    const int WAVE_BLOCKS = (N_NODES * 64 + 255) / 256;  // 12500
    const int GEMM_BLOCKS = (N_NODES + 127) / 128;       // 391 (128 nodes/block)
    const size_t HS = (size_t)N_NODES * 64;              // per-relation h/x stride
    const size_t VS = (size_t)N_NODES;                   // per-relation asv/adv stride

    // batched CSR build for all 3 relations (5 launches, no global atomics)
    partA_hist<<<R_REL * NBLK, 256, 0, stream>>>(edge_index, bh);
    partA2_scan<<<R_REL * NBUCK, 256, 0, stream>>>(bh, bhoff, btot);
    partA3_scan<<<R_REL, 256, 0, stream>>>(btot, bbase);
    partB_scatter<<<R_REL * NBLK, 256, 0, stream>>>(edge_index, edge_weight,
                                                    bh, bhoff, bbase, sedge);
    partC_sort<<<R_REL * NBUCK, 256, 0, stream>>>(bbase, sedge, rs);

    if (K == 3) {
        // layer-lockstep: one gemm + one agg dispatch per layer, grid.y = 3 relations
        for (int i = 0; i < 3; ++i) {
            if (i == 0)
                gemm_alpha_kernel<D_IN><<<dim3(GEMM_BLOCKS, 3), 256, 0, stream>>>(
                    x, 0, W0, (size_t)D_IN * H_DIM,
                    a_src + i * H_DIM, a_dst + i * H_DIM, 3 * H_DIM,
                    hbuf, HS, asv, adv, VS, 0);
            else
                gemm_alpha_kernel<H_DIM><<<dim3(GEMM_BLOCKS, 3), 256, 0, stream>>>(
                    xbuf, HS, (i == 1 ? W1 : W2), (size_t)H_DIM * H_DIM,
                    a_src + i * H_DIM, a_dst + i * H_DIM, 3 * H_DIM,
                    hbuf, HS, asv, adv, VS, 0);
            if (i < 2)
                agg_kernel<<<dim3(WAVE_BLOCKS, 3), 256, 0, stream>>>(
                    rs, sedge, asv, adv, VS, hbuf, HS,
                    bias + i * H_DIM, 3 * H_DIM,
                    xbuf, HS, 64, 1, 0);
            else
                agg_kernel<<<dim3(WAVE_BLOCKS, 3), 256, 0, stream>>>(
                    rs, sedge, asv, adv, VS, hbuf, HS,
                    bias + i * H_DIM, 3 * H_DIM,
                    out, 64, 192, 0, 0);
        }
    } else {
        for (int r = 0; r < R_REL; ++r) {
            for (int i = 0; i < 3; ++i) {
                if (i == 0)
                    gemm_alpha_kernel<D_IN><<<dim3(GEMM_BLOCKS, 1), 256, 0, stream>>>(
                        x, 0, W0, (size_t)D_IN * H_DIM,
                        a_src + i * H_DIM, a_dst + i * H_DIM, 3 * H_DIM,
                        hbuf, 0, asv, adv, 0, r);
                else
                    gemm_alpha_kernel<H_DIM><<<dim3(GEMM_BLOCKS, 1), 256, 0, stream>>>(
                        xbuf, 0, (i == 1 ? W1 : W2), (size_t)H_DIM * H_DIM,
                        a_src + i * H_DIM, a_dst + i * H_DIM, 3 * H_DIM,
                        hbuf, 0, asv, adv, 0, r);
                if (i < 2)
                    agg_kernel<<<dim3(WAVE_BLOCKS, 1), 256, 0, stream>>>(
                        rs, sedge, asv, adv, 0, hbuf, 0,
                        bias + i * H_DIM, 3 * H_DIM,
                        xbuf, 0, 64, 1, r);
                else
                    agg_kernel<<<dim3(WAVE_BLOCKS, 1), 256, 0, stream>>>(
                        rs, sedge, asv, adv, 0, hbuf, 0,
                        bias + i * H_DIM, 3 * H_DIM,
                        out + r * 64, 0, 192, 0, r);
            }
        }
    }
}

// Round 14
// 738.881 us; speedup vs baseline: 1.2989x; 1.2989x over previous
//
#include <hip/hip_runtime.h>
#include <math.h>

#define N_NODES 50000
#define E_EDGES 1600000
#define D_IN 128
#define H_DIM 64
#define R_REL 3
#define ETOT (E_EDGES + N_NODES)
#define NEG_SLOPE 0.2f

// radix-partition CSR build parameters
#define BSHIFT 7
#define BSIZE 128                              // dst nodes per bucket
#define NBUCK ((N_NODES + BSIZE - 1) / BSIZE)  // 391
#define CHUNK 7168                             // edges per block in passes A/B (56KB stage)
#define NBLK ((ETOT + CHUNK - 1) / CHUNK)      // 231
#define CCAP 5120                              // partC LDS stage capacity (40KB)

typedef int i32x2 __attribute__((ext_vector_type(2)));
typedef float f32x4 __attribute__((ext_vector_type(4)));

// ---------------- thread-tiled LDS GEMM + attention coefficients ----------------
// Block: 256 threads -> 64 nodes x 64 cols. Thread (tn,tc) computes a 4x4 tile.
// PROVEN round-9/11 version: VGPR ~44, no spill, ~50-75us batched.
// Tiling is CLOSED: both 8x8 (r10) and scalarized 8x4 (r13) spilled to scratch
// (VGPR 256, 350MB scratch WRITE, 10% occupancy) — full k4 unroll hoists loads
// across iterations and liveness scales with row count. Do not widen.
template <int DIN>
__global__ __launch_bounds__(256) void gemm_alpha_kernel(
    const float* __restrict__ xin, size_t xin_rstride,
    const float* __restrict__ W, size_t W_rstride,
    const float* __restrict__ a_s, const float* __restrict__ a_d, size_t a_rstride,
    float* __restrict__ h, size_t h_rstride,
    float* __restrict__ as_out, float* __restrict__ ad_out, size_t v_rstride,
    int r0)
{
    int rr = blockIdx.y;
    int rW = r0 + rr;
    xin += (size_t)rr * xin_rstride;
    W += (size_t)rW * W_rstride;
    a_s += (size_t)rW * a_rstride;
    a_d += (size_t)rW * a_rstride;
    h += (size_t)rr * h_rstride;
    as_out += (size_t)rr * v_rstride;
    ad_out += (size_t)rr * v_rstride;

    constexpr int KC = 64;
    constexpr int XSTR = KC + 4;
    __shared__ __align__(16) float xls[64 * XSTR];
    __shared__ __align__(16) float wls[KC * 64];
    int t = threadIdx.x;
    int n0 = blockIdx.x * 64;
    int nrows = N_NODES - n0; if (nrows > 64) nrows = 64;
    int tn = t >> 4;
    int tc = t & 15;

    float4 acc[4] = {{0,0,0,0},{0,0,0,0},{0,0,0,0},{0,0,0,0}};

    for (int kc = 0; kc < DIN; kc += KC) {
        if (kc) __syncthreads();
        int nf4 = nrows * (KC / 4);
        for (int f = t; f < nf4; f += 256) {
            int row = f >> 4;
            int q = f & 15;
            float4 xv = *reinterpret_cast<const float4*>(
                xin + (size_t)(n0 + row) * DIN + kc + q * 4);
            *reinterpret_cast<float4*>(&xls[row * XSTR + q * 4]) = xv;
        }
        for (int f = t; f < KC * 16; f += 256) {
            int kk = f >> 4;
            int q = f & 15;
            *reinterpret_cast<float4*>(&wls[kk * 64 + q * 4]) =
                *reinterpret_cast<const float4*>(W + (size_t)(kc + kk) * 64 + q * 4);
        }
        __syncthreads();

#pragma unroll
        for (int k4 = 0; k4 < KC / 4; ++k4) {
            float4 av[4], bv[4];
#pragma unroll
            for (int i = 0; i < 4; ++i)
                av[i] = *reinterpret_cast<const float4*>(
                    &xls[(tn * 4 + i) * XSTR + k4 * 4]);
#pragma unroll
            for (int u = 0; u < 4; ++u)
                bv[u] = *reinterpret_cast<const float4*>(
                    &wls[(k4 * 4 + u) * 64 + tc * 4]);
#pragma unroll
            for (int i = 0; i < 4; ++i) {
                acc[i].x = fmaf(av[i].x, bv[0].x, acc[i].x);
                acc[i].y = fmaf(av[i].x, bv[0].y, acc[i].y);
                acc[i].z = fmaf(av[i].x, bv[0].z, acc[i].z);
                acc[i].w = fmaf(av[i].x, bv[0].w, acc[i].w);
                acc[i].x = fmaf(av[i].y, bv[1].x, acc[i].x);
                acc[i].y = fmaf(av[i].y, bv[1].y, acc[i].y);
                acc[i].z = fmaf(av[i].y, bv[1].z, acc[i].z);
                acc[i].w = fmaf(av[i].y, bv[1].w, acc[i].w);
                acc[i].x = fmaf(av[i].z, bv[2].x, acc[i].x);
                acc[i].y = fmaf(av[i].z, bv[2].y, acc[i].y);
                acc[i].z = fmaf(av[i].z, bv[2].z, acc[i].z);
                acc[i].w = fmaf(av[i].z, bv[2].w, acc[i].w);
                acc[i].x = fmaf(av[i].w, bv[3].x, acc[i].x);
                acc[i].y = fmaf(av[i].w, bv[3].y, acc[i].y);
                acc[i].z = fmaf(av[i].w, bv[3].z, acc[i].z);
                acc[i].w = fmaf(av[i].w, bv[3].w, acc[i].w);
            }
        }
    }

    float4 asj = *reinterpret_cast<const float4*>(a_s + tc * 4);
    float4 adj = *reinterpret_cast<const float4*>(a_d + tc * 4);
#pragma unroll
    for (int i = 0; i < 4; ++i) {
        int node = n0 + tn * 4 + i;
        bool ok = node < N_NODES;
        if (ok)
            *reinterpret_cast<float4*>(h + (size_t)node * 64 + tc * 4) = acc[i];
        float vs = acc[i].x * asj.x + acc[i].y * asj.y +
                   acc[i].z * asj.z + acc[i].w * asj.w;
        float vd = acc[i].x * adj.x + acc[i].y * adj.y +
                   acc[i].z * adj.z + acc[i].w * adj.w;
#pragma unroll
        for (int m = 8; m >= 1; m >>= 1) {
            vs += __shfl_xor(vs, m, 64);
            vd += __shfl_xor(vd, m, 64);
        }
        if (ok && tc == 0) {
            as_out[node] = vs;
            ad_out[node] = vd;
        }
    }
}

// ---------------- radix-partitioned CSR build (batched over relations) ----------------
// Pass A: per-block LDS histogram over NBUCK dst-buckets. bh layout: [r][blk][bucket]
__global__ __launch_bounds__(256) void partA_hist(const int* __restrict__ edge_index,
                                                  int* __restrict__ bh)
{
    __shared__ int hist[NBUCK];
    int t = threadIdx.x;
    int r = blockIdx.x / NBLK;
    int blk = blockIdx.x % NBLK;
    const int* dstE = edge_index + (size_t)r * 2 * E_EDGES + E_EDGES;
    for (int b = t; b < NBUCK; b += 256) hist[b] = 0;
    __syncthreads();
    int base = blk * CHUNK;
#pragma unroll 4
    for (int u = 0; u < CHUNK / 256; ++u) {
        int i = base + u * 256 + t;
        if (i < ETOT) {
            int d = (i < E_EDGES) ? dstE[i] : (i - E_EDGES);
            atomicAdd(&hist[d >> BSHIFT], 1);
        }
    }
    __syncthreads();
    int* bh_blk = bh + ((size_t)r * NBLK + blk) * NBUCK;
    for (int b = t; b < NBUCK; b += 256) bh_blk[b] = hist[b];
}

// Pass A2: per (r,bucket), exclusive scan of per-block counts -> bhoff + total.
__global__ __launch_bounds__(256) void partA2_scan(const int* __restrict__ bh,
                                                   int* __restrict__ bhoff,
                                                   int* __restrict__ btot)
{
    __shared__ int tmp[256];
    int r = blockIdx.x / NBUCK;
    int b = blockIdx.x % NBUCK;
    int t = threadIdx.x;
    const int* bh_r = bh + (size_t)r * NBLK * NBUCK;
    int* bhoff_r = bhoff + (size_t)r * NBLK * NBUCK;
    int v = (t < NBLK) ? bh_r[(size_t)t * NBUCK + b] : 0;   // NBLK=231 <= 256
    int x = v;
#pragma unroll
    for (int off = 1; off < 256; off <<= 1) {
        tmp[t] = x;
        __syncthreads();
        int a = (t >= off) ? tmp[t - off] : 0;
        __syncthreads();
        x += a;
    }
    if (t < NBLK) bhoff_r[(size_t)t * NBUCK + b] = x - v;
    if (t == 255) btot[r * NBUCK + b] = x;
}

// Pass A3: per relation, exclusive scan of bucket totals -> bucket bases.
__global__ __launch_bounds__(256) void partA3_scan(const int* __restrict__ btot,
                                                   int* __restrict__ bbase)
{
    __shared__ int tmp[256];
    __shared__ int carry_s;
    int r = blockIdx.x;
    int t = threadIdx.x;
    const int* row = btot + r * NBUCK;
    int* outb = bbase + r * (NBUCK + 1);
    if (t == 0) carry_s = 0;
    __syncthreads();
    for (int base = 0; base < NBUCK; base += 256) {
        int idx = base + t;
        int v = (idx < NBUCK) ? row[idx] : 0;
        int x = v;
#pragma unroll
        for (int off = 1; off < 256; off <<= 1) {
            tmp[t] = x;
            __syncthreads();
            int a = (t >= off) ? tmp[t - off] : 0;
            __syncthreads();
            x += a;
        }
        int carry = carry_s;
        if (idx < NBUCK) outb[idx] = carry + x - v;
        __syncthreads();
        if (t == 255) carry_s = carry + x;
        __syncthreads();
    }
    if (t == 0) outb[NBUCK] = carry_s;  // == ETOT
}

// Pass B: block-local LDS counting sort by bucket, then LINEAR coalesced write-out.
// Record: .x = src | (dst << 16) (both < 2^16), .y = w bits.
__global__ __launch_bounds__(256) void partB_scatter(
    const int* __restrict__ edge_index, const float* __restrict__ edge_weight,
    const int* __restrict__ bh, const int* __restrict__ bhoff,
    const int* __restrict__ bbase, int2* __restrict__ sedge)
{
    __shared__ int2 stage[CHUNK];     // 56 KB
    __shared__ int cur[NBUCK];
    __shared__ int gbase[NBUCK];
    __shared__ int tmp[256];
    __shared__ int carry_s;
    int t = threadIdx.x;
    int r = blockIdx.x / NBLK;
    int blk = blockIdx.x % NBLK;
    const int* srcE = edge_index + (size_t)r * 2 * E_EDGES;
    const int* dstE = srcE + E_EDGES;
    const float* ewr = edge_weight + (size_t)r * E_EDGES;
    const int* bh_blk = bh + ((size_t)r * NBLK + blk) * NBUCK;
    const int* bhoff_blk = bhoff + ((size_t)r * NBLK + blk) * NBUCK;
    const int* bbase_r = bbase + r * (NBUCK + 1);
    int2* se_r = sedge + (size_t)r * ETOT;

    if (t == 0) carry_s = 0;
    __syncthreads();
    for (int base = 0; base < NBUCK; base += 256) {
        int idx = base + t;
        int v = (idx < NBUCK) ? bh_blk[idx] : 0;
        int x = v;
#pragma unroll
        for (int off = 1; off < 256; off <<= 1) {
            tmp[t] = x;
            __syncthreads();
            int a = (t >= off) ? tmp[t - off] : 0;
            __syncthreads();
            x += a;
        }
        int carry = carry_s;
        if (idx < NBUCK) {
            int ls = carry + x - v;
            cur[idx] = ls;
            gbase[idx] = bbase_r[idx] + bhoff_blk[idx] - ls;
        }
        __syncthreads();
        if (t == 255) carry_s = carry + x;
        __syncthreads();
    }

    int base0 = blk * CHUNK;
    int chunkLen = ETOT - base0; if (chunkLen > CHUNK) chunkLen = CHUNK;
#pragma unroll 4
    for (int u = 0; u < CHUNK / 256; ++u) {
        int i = base0 + u * 256 + t;
        if (i < ETOT) {
            int s, d;
            float w;
            if (i < E_EDGES) {
                s = srcE[i]; d = dstE[i]; w = ewr[i];
            } else {
                s = d = i - E_EDGES; w = 1.0f;
            }
            int pos = atomicAdd(&cur[d >> BSHIFT], 1);  // LDS atomic
            int2 pay;
            pay.x = s | (d << 16);
            pay.y = __float_as_int(w);
            stage[pos] = pay;
        }
    }
    __syncthreads();
    for (int j = t; j < chunkLen; j += 256) {
        int2 rec = stage[j];
        int d = (int)(((unsigned)rec.x) >> 16);
        se_r[gbase[d >> BSHIFT] + j] = rec;
    }
}

// Pass C: per-bucket LDS-staged counting sort, IN PLACE in sedge -> rs + final {src,w}.
__global__ __launch_bounds__(256) void partC_sort(
    const int* __restrict__ bbase, int2* __restrict__ sedge,
    int* __restrict__ rs)
{
    __shared__ int2 stage[CCAP];   // 40 KB
    __shared__ int cnt[BSIZE];
    __shared__ int rsl[BSIZE];
    __shared__ int tmp[BSIZE];
    __shared__ int cur[BSIZE];
    int r = blockIdx.x / NBUCK;
    int b = blockIdx.x % NBUCK;
    int t = threadIdx.x;
    const int* bbase_r = bbase + r * (NBUCK + 1);
    int* rs_r = rs + r * (N_NODES + 1);
    int2* se_r = sedge + (size_t)r * ETOT;
    int lo = b * BSIZE;
    int nn = N_NODES - lo; if (nn > BSIZE) nn = BSIZE;
    int seg0 = bbase_r[b], seg1 = bbase_r[b + 1];
    int len = seg1 - seg0;
    if (t < BSIZE) { cnt[t] = 0; cur[t] = 0; }
    __syncthreads();
    for (int k = t; k < len; k += 256) {
        int2 pw = se_r[seg0 + k];   // coalesced read
        if (k < CCAP) stage[k] = pw;
        atomicAdd(&cnt[(pw.x >> 16) & (BSIZE - 1)], 1);
    }
    __syncthreads();
    int v = 0, x = 0;
    if (t < BSIZE) { v = cnt[t]; x = v; }
#pragma unroll
    for (int off = 1; off < BSIZE; off <<= 1) {
        if (t < BSIZE) tmp[t] = x;
        __syncthreads();
        int a = (t < BSIZE && t >= off) ? tmp[t - off] : 0;
        __syncthreads();
        x += a;
    }
    if (t < BSIZE) rsl[t] = x - v;  // local exclusive
    __syncthreads();
    if (t < nn) rs_r[lo + t] = seg0 + rsl[t];
    if (b == NBUCK - 1 && t == 0) rs_r[N_NODES] = seg1;
    for (int k = t; k < len; k += 256) {
        int2 pw = (k < CCAP) ? stage[k] : se_r[seg0 + k];
        int dlo = (pw.x >> 16) & (BSIZE - 1);
        int pos = rsl[dlo] + atomicAdd(&cur[dlo], 1);
        int2 rec;
        rec.x = pw.x & 0xFFFF;
        rec.y = pw.y;
        se_r[seg0 + pos] = rec;
    }
}

// ---------------- per-node softmax + aggregation (no max pass) ----------------
// One wave per dst node; blockIdx.y = relation. The <=64-edge chunk's gather is
// fully unrolled into 3 register groups + reuse: all (up to 12) float4 gathers
// issue BEFORE any FMA. Branches on rem are wave-uniform (free). Out-of-range
// shfl slots carry pq=0 (their h loads hit h[0], L1-hot, harmless).
// PROVEN round-13: dropped agg out of top-5 (was 148us at 8-gather pipeline).
__global__ __launch_bounds__(256) void agg_kernel(
    const int* __restrict__ rs, const int2* __restrict__ sedge,
    const float* __restrict__ as_v, const float* __restrict__ ad_v, size_t v_rstride,
    const float* __restrict__ h, size_t h_rstride,
    const float* __restrict__ bias, size_t b_rstride,
    float* __restrict__ out, size_t out_roffset, int out_stride, int do_relu,
    int r0)
{
    int rr = blockIdx.y;
    int rW = r0 + rr;
    rs += (size_t)rW * (N_NODES + 1);
    sedge += (size_t)rW * ETOT;
    as_v += (size_t)rr * v_rstride;
    ad_v += (size_t)rr * v_rstride;
    h += (size_t)rr * h_rstride;
    bias += (size_t)rW * b_rstride;
    out += (size_t)rr * out_roffset;

    int wave = (int)(((size_t)blockIdx.x * blockDim.x + threadIdx.x) >> 6);
    int lane = threadIdx.x & 63;
    if (wave >= N_NODES) return;
    int beg = rs[wave], end = rs[wave + 1];
    float ad_n = ad_v[wave];

    int sub = lane >> 4;   // edge sub-slot 0..3
    int f = lane & 15;     // feature quad index
    const float* hf = h + f * 4;

    float ssum = 0.f;
    float4 a0 = {0.f, 0.f, 0.f, 0.f};
    float4 a1 = a0, a2 = a0, a3 = a0;

// macros take explicit variable names (no token pasting: `X0.x` after `##`
// lexes as an invalid pp-number)
#define GLOAD(T0, S0, Q0, H0, S1, Q1, H1, S2, Q2, H2, S3, Q3, H3)             \
    S0 = __shfl(srcv, (T0) + sub, 64);                                        \
    Q0 = __shfl(pq, (T0) + sub, 64);                                          \
    S1 = __shfl(srcv, (T0) + 4 + sub, 64);                                    \
    Q1 = __shfl(pq, (T0) + 4 + sub, 64);                                      \
    S2 = __shfl(srcv, (T0) + 8 + sub, 64);                                    \
    Q2 = __shfl(pq, (T0) + 8 + sub, 64);                                      \
    S3 = __shfl(srcv, (T0) + 12 + sub, 64);                                   \
    Q3 = __shfl(pq, (T0) + 12 + sub, 64);                                     \
    H0 = *reinterpret_cast<const float4*>(hf + (size_t)S0 * 64);              \
    H1 = *reinterpret_cast<const float4*>(hf + (size_t)S1 * 64);              \
    H2 = *reinterpret_cast<const float4*>(hf + (size_t)S2 * 64);              \
    H3 = *reinterpret_cast<const float4*>(hf + (size_t)S3 * 64);

#define GFMA(Q0, H0, Q1, H1, Q2, H2, Q3, H3)                                  \
    a0.x = fmaf(Q0, H0.x, a0.x);                                              \
    a0.y = fmaf(Q0, H0.y, a0.y);                                              \
    a0.z = fmaf(Q0, H0.z, a0.z);                                              \
    a0.w = fmaf(Q0, H0.w, a0.w);                                              \
    a1.x = fmaf(Q1, H1.x, a1.x);                                              \
    a1.y = fmaf(Q1, H1.y, a1.y);                                              \
    a1.z = fmaf(Q1, H1.z, a1.z);                                              \
    a1.w = fmaf(Q1, H1.w, a1.w);                                              \
    a2.x = fmaf(Q2, H2.x, a2.x);                                              \
    a2.y = fmaf(Q2, H2.y, a2.y);                                              \
    a2.z = fmaf(Q2, H2.z, a2.z);                                              \
    a2.w = fmaf(Q2, H2.w, a2.w);                                              \
    a3.x = fmaf(Q3, H3.x, a3.x);                                              \
    a3.y = fmaf(Q3, H3.y, a3.y);                                              \
    a3.z = fmaf(Q3, H3.z, a3.z);                                              \
    a3.w = fmaf(Q3, H3.w, a3.w);

    for (int cbeg = beg; cbeg < end; cbeg += 64) {
        int rem = end - cbeg;
        if (rem > 64) rem = 64;
        int srcv = 0;
        float pq = 0.f;
        if (lane < rem) {
            i32x2 pe = __builtin_nontemporal_load(
                reinterpret_cast<const i32x2*>(sedge + cbeg + lane));
            srcv = pe.x;
            float e = as_v[srcv] + ad_n;
            e = (e > 0.f) ? e : NEG_SLOPE * e;
            float p = __expf(e);
            ssum += p;
            pq = p * __int_as_float(pe.y);
        }
        bool gB = rem > 16, gC = rem > 32, gD = rem > 48;
        int sA0, sA1, sA2, sA3, sB0 = 0, sB1 = 0, sB2 = 0, sB3 = 0;
        int sC0 = 0, sC1 = 0, sC2 = 0, sC3 = 0;
        float qA0, qA1, qA2, qA3, qB0 = 0.f, qB1 = 0.f, qB2 = 0.f, qB3 = 0.f;
        float qC0 = 0.f, qC1 = 0.f, qC2 = 0.f, qC3 = 0.f;
        float4 hA0, hA1, hA2, hA3, hB0, hB1, hB2, hB3, hC0, hC1, hC2, hC3;
        GLOAD(0, sA0, qA0, hA0, sA1, qA1, hA1, sA2, qA2, hA2, sA3, qA3, hA3)
        if (gB) { GLOAD(16, sB0, qB0, hB0, sB1, qB1, hB1, sB2, qB2, hB2, sB3, qB3, hB3) }
        if (gC) { GLOAD(32, sC0, qC0, hC0, sC1, qC1, hC1, sC2, qC2, hC2, sC3, qC3, hC3) }
        GFMA(qA0, hA0, qA1, hA1, qA2, hA2, qA3, hA3)
        if (gD) {  // reuse group-A registers for slots 48-63
            GLOAD(48, sA0, qA0, hA0, sA1, qA1, hA1, sA2, qA2, hA2, sA3, qA3, hA3)
        }
        if (gB) { GFMA(qB0, hB0, qB1, hB1, qB2, hB2, qB3, hB3) }
        if (gC) { GFMA(qC0, hC0, qC1, hC1, qC2, hC2, qC3, hC3) }
        if (gD) { GFMA(qA0, hA0, qA1, hA1, qA2, hA2, qA3, hA3) }
    }
#undef GLOAD
#undef GFMA

#pragma unroll
    for (int off = 32; off > 0; off >>= 1) ssum += __shfl_xor(ssum, off, 64);
    a0.x = (a0.x + a1.x) + (a2.x + a3.x);
    a0.y = (a0.y + a1.y) + (a2.y + a3.y);
    a0.z = (a0.z + a1.z) + (a2.z + a3.z);
    a0.w = (a0.w + a1.w) + (a2.w + a3.w);
    a0.x += __shfl_xor(a0.x, 16, 64);
    a0.y += __shfl_xor(a0.y, 16, 64);
    a0.z += __shfl_xor(a0.z, 16, 64);
    a0.w += __shfl_xor(a0.w, 16, 64);
    a0.x += __shfl_xor(a0.x, 32, 64);
    a0.y += __shfl_xor(a0.y, 32, 64);
    a0.z += __shfl_xor(a0.z, 32, 64);
    a0.w += __shfl_xor(a0.w, 32, 64);

    if (sub == 0) {
        float inv = 1.f / (ssum + 1e-16f);
        const float4 bv = *reinterpret_cast<const float4*>(bias + f * 4);
        float4 o;
        o.x = fmaf(a0.x, inv, bv.x);
        o.y = fmaf(a0.y, inv, bv.y);
        o.z = fmaf(a0.z, inv, bv.z);
        o.w = fmaf(a0.w, inv, bv.w);
        float* dst = out + (size_t)wave * out_stride + f * 4;
        if (do_relu) {
            o.x = fmaxf(o.x, 0.f);
            o.y = fmaxf(o.y, 0.f);
            o.z = fmaxf(o.z, 0.f);
            o.w = fmaxf(o.w, 0.f);
            *reinterpret_cast<float4*>(dst) = o;   // xbuf: re-read by next gemm
        } else {
            f32x4 o4 = {o.x, o.y, o.z, o.w};       // final out: never re-read
            __builtin_nontemporal_store(o4, reinterpret_cast<f32x4*>(dst));
        }
    }
}

extern "C" void kernel_launch(void* const* d_in, const int* in_sizes, int n_in,
                              void* d_out, int out_size, void* d_ws, size_t ws_size,
                              hipStream_t stream)
{
    (void)in_sizes; (void)n_in; (void)out_size;
    const float* x = (const float*)d_in[0];
    const float* edge_weight = (const float*)d_in[1];
    const float* W0 = (const float*)d_in[2];
    const float* W1 = (const float*)d_in[3];
    const float* W2 = (const float*)d_in[4];
    const float* a_src = (const float*)d_in[5];
    const float* a_dst = (const float*)d_in[6];
    const float* bias = (const float*)d_in[7];
    const int* edge_index = (const int*)d_in[8];
    float* out = (float*)d_out;

    char* ws = (char*)d_ws;
    size_t off = 0;
    auto alloc = [&](size_t bytes) {
        void* p = ws + off;
        off += (bytes + 255) & ~(size_t)255;
        return p;
    };
    int2* sedge = (int2*)alloc((size_t)R_REL * ETOT * 8);        // 39.6 MB
    int* bh = (int*)alloc((size_t)R_REL * NBLK * NBUCK * 4);     // 1.08 MB
    int* bhoff = (int*)alloc((size_t)R_REL * NBLK * NBUCK * 4);  // 1.08 MB
    int* btot = (int*)alloc((size_t)R_REL * NBUCK * 4);
    int* bbase = (int*)alloc((size_t)R_REL * (NBUCK + 1) * 4);
    int* rs = (int*)alloc((size_t)R_REL * (N_NODES + 1) * 4);

    // batched path needs 3x node buffers (~78 MB extra); fall back if ws too small
    size_t per_rel = ((size_t)N_NODES * 64 * 4 * 2 + (size_t)N_NODES * 4 * 2 + 1024);
    int K = (ws_size >= off + 3 * per_rel + (1 << 20)) ? 3 : 1;
    float* hbuf = (float*)alloc((size_t)K * N_NODES * 64 * 4);
    float* xbuf = (float*)alloc((size_t)K * N_NODES * 64 * 4);
    float* asv = (float*)alloc((size_t)K * N_NODES * 4);
    float* adv = (float*)alloc((size_t)K * N_NODES * 4);

    const int WAVE_BLOCKS = (N_NODES * 64 + 255) / 256;  // 12500
    const int GEMM_BLOCKS = (N_NODES + 63) / 64;         // 782 (64 nodes/block)
    const size_t HS = (size_t)N_NODES * 64;              // per-relation h/x stride
    const size_t VS = (size_t)N_NODES;                   // per-relation asv/adv stride

    // batched CSR build for all 3 relations (5 launches, no global atomics)
    partA_hist<<<R_REL * NBLK, 256, 0, stream>>>(edge_index, bh);
    partA2_scan<<<R_REL * NBUCK, 256, 0, stream>>>(bh, bhoff, btot);
    partA3_scan<<<R_REL, 256, 0, stream>>>(btot, bbase);
    partB_scatter<<<R_REL * NBLK, 256, 0, stream>>>(edge_index, edge_weight,
                                                    bh, bhoff, bbase, sedge);
    partC_sort<<<R_REL * NBUCK, 256, 0, stream>>>(bbase, sedge, rs);

    if (K == 3) {
        // layer-lockstep: one gemm + one agg dispatch per layer, grid.y = 3 relations
        for (int i = 0; i < 3; ++i) {
            if (i == 0)
                gemm_alpha_kernel<D_IN><<<dim3(GEMM_BLOCKS, 3), 256, 0, stream>>>(
                    x, 0, W0, (size_t)D_IN * H_DIM,
                    a_src + i * H_DIM, a_dst + i * H_DIM, 3 * H_DIM,
                    hbuf, HS, asv, adv, VS, 0);
            else
                gemm_alpha_kernel<H_DIM><<<dim3(GEMM_BLOCKS, 3), 256, 0, stream>>>(
                    xbuf, HS, (i == 1 ? W1 : W2), (size_t)H_DIM * H_DIM,
                    a_src + i * H_DIM, a_dst + i * H_DIM, 3 * H_DIM,
                    hbuf, HS, asv, adv, VS, 0);
            if (i < 2)
                agg_kernel<<<dim3(WAVE_BLOCKS, 3), 256, 0, stream>>>(
                    rs, sedge, asv, adv, VS, hbuf, HS,
                    bias + i * H_DIM, 3 * H_DIM,
                    xbuf, HS, 64, 1, 0);
            else
                agg_kernel<<<dim3(WAVE_BLOCKS, 3), 256, 0, stream>>>(
                    rs, sedge, asv, adv, VS, hbuf, HS,
                    bias + i * H_DIM, 3 * H_DIM,
                    out, 64, 192, 0, 0);
        }
    } else {
        for (int r = 0; r < R_REL; ++r) {
            for (int i = 0; i < 3; ++i) {
                if (i == 0)
                    gemm_alpha_kernel<D_IN><<<dim3(GEMM_BLOCKS, 1), 256, 0, stream>>>(
                        x, 0, W0, (size_t)D_IN * H_DIM,
                        a_src + i * H_DIM, a_dst + i * H_DIM, 3 * H_DIM,
                        hbuf, 0, asv, adv, 0, r);
                else
                    gemm_alpha_kernel<H_DIM><<<dim3(GEMM_BLOCKS, 1), 256, 0, stream>>>(
                        xbuf, 0, (i == 1 ? W1 : W2), (size_t)H_DIM * H_DIM,
                        a_src + i * H_DIM, a_dst + i * H_DIM, 3 * H_DIM,
                        hbuf, 0, asv, adv, 0, r);
                if (i < 2)
                    agg_kernel<<<dim3(WAVE_BLOCKS, 1), 256, 0, stream>>>(
                        rs, sedge, asv, adv, 0, hbuf, 0,
                        bias + i * H_DIM, 3 * H_DIM,
                        xbuf, 0, 64, 1, r);
                else
                    agg_kernel<<<dim3(WAVE_BLOCKS, 1), 256, 0, stream>>>(
                        rs, sedge, asv, adv, 0, hbuf, 0,
                        bias + i * H_DIM, 3 * H_DIM,
                        out + r * 64, 0, 192, 0, r);
            }
        }
    }
}

// Round 15
// 719.456 us; speedup vs baseline: 1.3340x; 1.0270x over previous
//
#include <hip/hip_runtime.h>
#include <math.h>

#define N_NODES 50000
#define E_EDGES 1600000
#define D_IN 128
#define H_DIM 64
#define R_REL 3
#define ETOT (E_EDGES + N_NODES)
#define NEG_SLOPE 0.2f

// radix-partition CSR build parameters
#define BSHIFT 7
#define BSIZE 128                              // dst nodes per bucket
#define NBUCK ((N_NODES + BSIZE - 1) / BSIZE)  // 391
#define CHUNK 7168                             // edges per block in passes A/B (56KB stage)
#define NBLK ((ETOT + CHUNK - 1) / CHUNK)      // 231
#define CCAP 5120                              // partC LDS stage capacity (40KB)

typedef int i32x2 __attribute__((ext_vector_type(2)));
typedef float f32x4 __attribute__((ext_vector_type(4)));

// ---------------- thread-tiled LDS GEMM + attention coefficients ----------------
// Block: 256 threads -> 64 nodes x 64 cols. Thread (tn,tc) computes a 4x4 tile.
// PROVEN round-9/11 version: VGPR ~44, no spill. Tiling is CLOSED: 8x8 (r10)
// and scalarized 8x4 (r13) both spilled (VGPR 256, 350MB scratch WRITE).
template <int DIN>
__global__ __launch_bounds__(256) void gemm_alpha_kernel(
    const float* __restrict__ xin, size_t xin_rstride,
    const float* __restrict__ W, size_t W_rstride,
    const float* __restrict__ a_s, const float* __restrict__ a_d, size_t a_rstride,
    float* __restrict__ h, size_t h_rstride,
    float* __restrict__ as_out, float* __restrict__ ad_out, size_t v_rstride,
    int r0)
{
    int rr = blockIdx.y;
    int rW = r0 + rr;
    xin += (size_t)rr * xin_rstride;
    W += (size_t)rW * W_rstride;
    a_s += (size_t)rW * a_rstride;
    a_d += (size_t)rW * a_rstride;
    h += (size_t)rr * h_rstride;
    as_out += (size_t)rr * v_rstride;
    ad_out += (size_t)rr * v_rstride;

    constexpr int KC = 64;
    constexpr int XSTR = KC + 4;
    __shared__ __align__(16) float xls[64 * XSTR];
    __shared__ __align__(16) float wls[KC * 64];
    int t = threadIdx.x;
    int n0 = blockIdx.x * 64;
    int nrows = N_NODES - n0; if (nrows > 64) nrows = 64;
    int tn = t >> 4;
    int tc = t & 15;

    float4 acc[4] = {{0,0,0,0},{0,0,0,0},{0,0,0,0},{0,0,0,0}};

    for (int kc = 0; kc < DIN; kc += KC) {
        if (kc) __syncthreads();
        int nf4 = nrows * (KC / 4);
        for (int f = t; f < nf4; f += 256) {
            int row = f >> 4;
            int q = f & 15;
            float4 xv = *reinterpret_cast<const float4*>(
                xin + (size_t)(n0 + row) * DIN + kc + q * 4);
            *reinterpret_cast<float4*>(&xls[row * XSTR + q * 4]) = xv;
        }
        for (int f = t; f < KC * 16; f += 256) {
            int kk = f >> 4;
            int q = f & 15;
            *reinterpret_cast<float4*>(&wls[kk * 64 + q * 4]) =
                *reinterpret_cast<const float4*>(W + (size_t)(kc + kk) * 64 + q * 4);
        }
        __syncthreads();

#pragma unroll
        for (int k4 = 0; k4 < KC / 4; ++k4) {
            float4 av[4], bv[4];
#pragma unroll
            for (int i = 0; i < 4; ++i)
                av[i] = *reinterpret_cast<const float4*>(
                    &xls[(tn * 4 + i) * XSTR + k4 * 4]);
#pragma unroll
            for (int u = 0; u < 4; ++u)
                bv[u] = *reinterpret_cast<const float4*>(
                    &wls[(k4 * 4 + u) * 64 + tc * 4]);
#pragma unroll
            for (int i = 0; i < 4; ++i) {
                acc[i].x = fmaf(av[i].x, bv[0].x, acc[i].x);
                acc[i].y = fmaf(av[i].x, bv[0].y, acc[i].y);
                acc[i].z = fmaf(av[i].x, bv[0].z, acc[i].z);
                acc[i].w = fmaf(av[i].x, bv[0].w, acc[i].w);
                acc[i].x = fmaf(av[i].y, bv[1].x, acc[i].x);
                acc[i].y = fmaf(av[i].y, bv[1].y, acc[i].y);
                acc[i].z = fmaf(av[i].y, bv[1].z, acc[i].z);
                acc[i].w = fmaf(av[i].y, bv[1].w, acc[i].w);
                acc[i].x = fmaf(av[i].z, bv[2].x, acc[i].x);
                acc[i].y = fmaf(av[i].z, bv[2].y, acc[i].y);
                acc[i].z = fmaf(av[i].z, bv[2].z, acc[i].z);
                acc[i].w = fmaf(av[i].z, bv[2].w, acc[i].w);
                acc[i].x = fmaf(av[i].w, bv[3].x, acc[i].x);
                acc[i].y = fmaf(av[i].w, bv[3].y, acc[i].y);
                acc[i].z = fmaf(av[i].w, bv[3].z, acc[i].z);
                acc[i].w = fmaf(av[i].w, bv[3].w, acc[i].w);
            }
        }
    }

    float4 asj = *reinterpret_cast<const float4*>(a_s + tc * 4);
    float4 adj = *reinterpret_cast<const float4*>(a_d + tc * 4);
#pragma unroll
    for (int i = 0; i < 4; ++i) {
        int node = n0 + tn * 4 + i;
        bool ok = node < N_NODES;
        if (ok)
            *reinterpret_cast<float4*>(h + (size_t)node * 64 + tc * 4) = acc[i];
        float vs = acc[i].x * asj.x + acc[i].y * asj.y +
                   acc[i].z * asj.z + acc[i].w * asj.w;
        float vd = acc[i].x * adj.x + acc[i].y * adj.y +
                   acc[i].z * adj.z + acc[i].w * adj.w;
#pragma unroll
        for (int m = 8; m >= 1; m >>= 1) {
            vs += __shfl_xor(vs, m, 64);
            vd += __shfl_xor(vd, m, 64);
        }
        if (ok && tc == 0) {
            as_out[node] = vs;
            ad_out[node] = vd;
        }
    }
}

// ---------------- radix-partitioned CSR build (batched over relations) ----------------
__global__ __launch_bounds__(256) void partA_hist(const int* __restrict__ edge_index,
                                                  int* __restrict__ bh)
{
    __shared__ int hist[NBUCK];
    int t = threadIdx.x;
    int r = blockIdx.x / NBLK;
    int blk = blockIdx.x % NBLK;
    const int* dstE = edge_index + (size_t)r * 2 * E_EDGES + E_EDGES;
    for (int b = t; b < NBUCK; b += 256) hist[b] = 0;
    __syncthreads();
    int base = blk * CHUNK;
#pragma unroll 4
    for (int u = 0; u < CHUNK / 256; ++u) {
        int i = base + u * 256 + t;
        if (i < ETOT) {
            int d = (i < E_EDGES) ? dstE[i] : (i - E_EDGES);
            atomicAdd(&hist[d >> BSHIFT], 1);
        }
    }
    __syncthreads();
    int* bh_blk = bh + ((size_t)r * NBLK + blk) * NBUCK;
    for (int b = t; b < NBUCK; b += 256) bh_blk[b] = hist[b];
}

__global__ __launch_bounds__(256) void partA2_scan(const int* __restrict__ bh,
                                                   int* __restrict__ bhoff,
                                                   int* __restrict__ btot)
{
    __shared__ int tmp[256];
    int r = blockIdx.x / NBUCK;
    int b = blockIdx.x % NBUCK;
    int t = threadIdx.x;
    const int* bh_r = bh + (size_t)r * NBLK * NBUCK;
    int* bhoff_r = bhoff + (size_t)r * NBLK * NBUCK;
    int v = (t < NBLK) ? bh_r[(size_t)t * NBUCK + b] : 0;   // NBLK=231 <= 256
    int x = v;
#pragma unroll
    for (int off = 1; off < 256; off <<= 1) {
        tmp[t] = x;
        __syncthreads();
        int a = (t >= off) ? tmp[t - off] : 0;
        __syncthreads();
        x += a;
    }
    if (t < NBLK) bhoff_r[(size_t)t * NBUCK + b] = x - v;
    if (t == 255) btot[r * NBUCK + b] = x;
}

__global__ __launch_bounds__(256) void partA3_scan(const int* __restrict__ btot,
                                                   int* __restrict__ bbase)
{
    __shared__ int tmp[256];
    __shared__ int carry_s;
    int r = blockIdx.x;
    int t = threadIdx.x;
    const int* row = btot + r * NBUCK;
    int* outb = bbase + r * (NBUCK + 1);
    if (t == 0) carry_s = 0;
    __syncthreads();
    for (int base = 0; base < NBUCK; base += 256) {
        int idx = base + t;
        int v = (idx < NBUCK) ? row[idx] : 0;
        int x = v;
#pragma unroll
        for (int off = 1; off < 256; off <<= 1) {
            tmp[t] = x;
            __syncthreads();
            int a = (t >= off) ? tmp[t - off] : 0;
            __syncthreads();
            x += a;
        }
        int carry = carry_s;
        if (idx < NBUCK) outb[idx] = carry + x - v;
        __syncthreads();
        if (t == 255) carry_s = carry + x;
        __syncthreads();
    }
    if (t == 0) outb[NBUCK] = carry_s;  // == ETOT
}

// Pass B: block-local LDS counting sort by bucket, then LINEAR coalesced write-out.
__global__ __launch_bounds__(256) void partB_scatter(
    const int* __restrict__ edge_index, const float* __restrict__ edge_weight,
    const int* __restrict__ bh, const int* __restrict__ bhoff,
    const int* __restrict__ bbase, int2* __restrict__ sedge)
{
    __shared__ int2 stage[CHUNK];     // 56 KB
    __shared__ int cur[NBUCK];
    __shared__ int gbase[NBUCK];
    __shared__ int tmp[256];
    __shared__ int carry_s;
    int t = threadIdx.x;
    int r = blockIdx.x / NBLK;
    int blk = blockIdx.x % NBLK;
    const int* srcE = edge_index + (size_t)r * 2 * E_EDGES;
    const int* dstE = srcE + E_EDGES;
    const float* ewr = edge_weight + (size_t)r * E_EDGES;
    const int* bh_blk = bh + ((size_t)r * NBLK + blk) * NBUCK;
    const int* bhoff_blk = bhoff + ((size_t)r * NBLK + blk) * NBUCK;
    const int* bbase_r = bbase + r * (NBUCK + 1);
    int2* se_r = sedge + (size_t)r * ETOT;

    if (t == 0) carry_s = 0;
    __syncthreads();
    for (int base = 0; base < NBUCK; base += 256) {
        int idx = base + t;
        int v = (idx < NBUCK) ? bh_blk[idx] : 0;
        int x = v;
#pragma unroll
        for (int off = 1; off < 256; off <<= 1) {
            tmp[t] = x;
            __syncthreads();
            int a = (t >= off) ? tmp[t - off] : 0;
            __syncthreads();
            x += a;
        }
        int carry = carry_s;
        if (idx < NBUCK) {
            int ls = carry + x - v;
            cur[idx] = ls;
            gbase[idx] = bbase_r[idx] + bhoff_blk[idx] - ls;
        }
        __syncthreads();
        if (t == 255) carry_s = carry + x;
        __syncthreads();
    }

    int base0 = blk * CHUNK;
    int chunkLen = ETOT - base0; if (chunkLen > CHUNK) chunkLen = CHUNK;
#pragma unroll 4
    for (int u = 0; u < CHUNK / 256; ++u) {
        int i = base0 + u * 256 + t;
        if (i < ETOT) {
            int s, d;
            float w;
            if (i < E_EDGES) {
                s = srcE[i]; d = dstE[i]; w = ewr[i];
            } else {
                s = d = i - E_EDGES; w = 1.0f;
            }
            int pos = atomicAdd(&cur[d >> BSHIFT], 1);  // LDS atomic
            int2 pay;
            pay.x = s | (d << 16);
            pay.y = __float_as_int(w);
            stage[pos] = pay;
        }
    }
    __syncthreads();
    for (int j = t; j < chunkLen; j += 256) {
        int2 rec = stage[j];
        int d = (int)(((unsigned)rec.x) >> 16);
        se_r[gbase[d >> BSHIFT] + j] = rec;
    }
}

// Pass C: per-bucket LDS-staged counting sort, IN PLACE in sedge -> rs + final {src,w}.
__global__ __launch_bounds__(256) void partC_sort(
    const int* __restrict__ bbase, int2* __restrict__ sedge,
    int* __restrict__ rs)
{
    __shared__ int2 stage[CCAP];   // 40 KB
    __shared__ int cnt[BSIZE];
    __shared__ int rsl[BSIZE];
    __shared__ int tmp[BSIZE];
    __shared__ int cur[BSIZE];
    int r = blockIdx.x / NBUCK;
    int b = blockIdx.x % NBUCK;
    int t = threadIdx.x;
    const int* bbase_r = bbase + r * (NBUCK + 1);
    int* rs_r = rs + r * (N_NODES + 1);
    int2* se_r = sedge + (size_t)r * ETOT;
    int lo = b * BSIZE;
    int nn = N_NODES - lo; if (nn > BSIZE) nn = BSIZE;
    int seg0 = bbase_r[b], seg1 = bbase_r[b + 1];
    int len = seg1 - seg0;
    if (t < BSIZE) { cnt[t] = 0; cur[t] = 0; }
    __syncthreads();
    for (int k = t; k < len; k += 256) {
        int2 pw = se_r[seg0 + k];   // coalesced read
        if (k < CCAP) stage[k] = pw;
        atomicAdd(&cnt[(pw.x >> 16) & (BSIZE - 1)], 1);
    }
    __syncthreads();
    int v = 0, x = 0;
    if (t < BSIZE) { v = cnt[t]; x = v; }
#pragma unroll
    for (int off = 1; off < BSIZE; off <<= 1) {
        if (t < BSIZE) tmp[t] = x;
        __syncthreads();
        int a = (t < BSIZE && t >= off) ? tmp[t - off] : 0;
        __syncthreads();
        x += a;
    }
    if (t < BSIZE) rsl[t] = x - v;  // local exclusive
    __syncthreads();
    if (t < nn) rs_r[lo + t] = seg0 + rsl[t];
    if (b == NBUCK - 1 && t == 0) rs_r[N_NODES] = seg1;
    for (int k = t; k < len; k += 256) {
        int2 pw = (k < CCAP) ? stage[k] : se_r[seg0 + k];
        int dlo = (pw.x >> 16) & (BSIZE - 1);
        int pos = rsl[dlo] + atomicAdd(&cur[dlo], 1);
        int2 rec;
        rec.x = pw.x & 0xFFFF;
        rec.y = pw.y;
        se_r[seg0 + pos] = rec;
    }
}

// ---------------- per-node softmax + aggregation (no max pass) ----------------
// TWO dst nodes per wave: lanes 0-31 = node 2*wv, lanes 32-63 = node 2*wv+1.
// Halves wave count & per-node fixed overhead (prologue/epilogue), keeps the
// proven r11 2-stage pipelined gather per half: 4 chains x float4 per half
// (8 rows in flight per wave). Chunk = 32 edges per half; all shuffles and
// xor-reductions stay within the 32-lane half.
__global__ __launch_bounds__(256) void agg_kernel(
    const int* __restrict__ rs, const int2* __restrict__ sedge,
    const float* __restrict__ as_v, const float* __restrict__ ad_v, size_t v_rstride,
    const float* __restrict__ h, size_t h_rstride,
    const float* __restrict__ bias, size_t b_rstride,
    float* __restrict__ out, size_t out_roffset, int out_stride, int do_relu,
    int r0)
{
    int rr = blockIdx.y;
    int rW = r0 + rr;
    rs += (size_t)rW * (N_NODES + 1);
    sedge += (size_t)rW * ETOT;
    as_v += (size_t)rr * v_rstride;
    ad_v += (size_t)rr * v_rstride;
    h += (size_t)rr * h_rstride;
    bias += (size_t)rW * b_rstride;
    out += (size_t)rr * out_roffset;

    int wv = (int)(((size_t)blockIdx.x * blockDim.x + threadIdx.x) >> 6);
    int lane = threadIdx.x & 63;
    if (wv >= (N_NODES + 1) / 2) return;
    int half = lane >> 5;   // 0 or 1
    int hl = lane & 31;     // lane within half
    int node = wv * 2 + half;
    bool nok = node < N_NODES;   // N even -> always true; keep guard
    int beg = 0, end = 0;
    float ad_n = 0.f;
    if (nok) {
        beg = rs[node];
        end = rs[node + 1];
        ad_n = ad_v[node];
    }

    int sub = hl >> 4;     // sub-slot 0..1 within half
    int f = hl & 15;       // feature quad index
    int hb = half << 5;    // shfl base lane for this half
    const float* hf = h + f * 4;

    float ssum = 0.f;
    float4 a0 = {0.f, 0.f, 0.f, 0.f};
    float4 a1 = a0, a2 = a0, a3 = a0;

    for (int cbeg = beg; cbeg < end; cbeg += 32) {
        int rem = end - cbeg;
        if (rem > 32) rem = 32;
        int srcv = 0;
        float pq = 0.f;
        if (hl < rem) {
            i32x2 pe = __builtin_nontemporal_load(
                reinterpret_cast<const i32x2*>(sedge + cbeg + hl));
            srcv = pe.x;
            float e = as_v[srcv] + ad_n;
            e = (e > 0.f) ? e : NEG_SLOPE * e;
            float p = __expf(e);
            ssum += p;
            pq = p * __int_as_float(pe.y);
        }
        // 4 chains, slots t0 + j*2 + sub (j=0..3 covers t0..t0+7), 2-stage pipeline
        int s0 = __shfl(srcv, hb + 0 + sub, 64);
        float q0 = __shfl(pq, hb + 0 + sub, 64);
        int s1 = __shfl(srcv, hb + 2 + sub, 64);
        float q1 = __shfl(pq, hb + 2 + sub, 64);
        int s2 = __shfl(srcv, hb + 4 + sub, 64);
        float q2 = __shfl(pq, hb + 4 + sub, 64);
        int s3 = __shfl(srcv, hb + 6 + sub, 64);
        float q3 = __shfl(pq, hb + 6 + sub, 64);
        float4 h0 = *reinterpret_cast<const float4*>(hf + (size_t)s0 * 64);
        float4 h1 = *reinterpret_cast<const float4*>(hf + (size_t)s1 * 64);
        float4 h2 = *reinterpret_cast<const float4*>(hf + (size_t)s2 * 64);
        float4 h3 = *reinterpret_cast<const float4*>(hf + (size_t)s3 * 64);
        for (int t0 = 8; t0 < rem; t0 += 8) {
            int ns0 = __shfl(srcv, hb + t0 + 0 + sub, 64);
            float nq0 = __shfl(pq, hb + t0 + 0 + sub, 64);
            int ns1 = __shfl(srcv, hb + t0 + 2 + sub, 64);
            float nq1 = __shfl(pq, hb + t0 + 2 + sub, 64);
            int ns2 = __shfl(srcv, hb + t0 + 4 + sub, 64);
            float nq2 = __shfl(pq, hb + t0 + 4 + sub, 64);
            int ns3 = __shfl(srcv, hb + t0 + 6 + sub, 64);
            float nq3 = __shfl(pq, hb + t0 + 6 + sub, 64);
            float4 nh0 = *reinterpret_cast<const float4*>(hf + (size_t)ns0 * 64);
            float4 nh1 = *reinterpret_cast<const float4*>(hf + (size_t)ns1 * 64);
            float4 nh2 = *reinterpret_cast<const float4*>(hf + (size_t)ns2 * 64);
            float4 nh3 = *reinterpret_cast<const float4*>(hf + (size_t)ns3 * 64);
            a0.x = fmaf(q0, h0.x, a0.x);
            a0.y = fmaf(q0, h0.y, a0.y);
            a0.z = fmaf(q0, h0.z, a0.z);
            a0.w = fmaf(q0, h0.w, a0.w);
            a1.x = fmaf(q1, h1.x, a1.x);
            a1.y = fmaf(q1, h1.y, a1.y);
            a1.z = fmaf(q1, h1.z, a1.z);
            a1.w = fmaf(q1, h1.w, a1.w);
            a2.x = fmaf(q2, h2.x, a2.x);
            a2.y = fmaf(q2, h2.y, a2.y);
            a2.z = fmaf(q2, h2.z, a2.z);
            a2.w = fmaf(q2, h2.w, a2.w);
            a3.x = fmaf(q3, h3.x, a3.x);
            a3.y = fmaf(q3, h3.y, a3.y);
            a3.z = fmaf(q3, h3.z, a3.z);
            a3.w = fmaf(q3, h3.w, a3.w);
            q0 = nq0; h0 = nh0;
            q1 = nq1; h1 = nh1;
            q2 = nq2; h2 = nh2;
            q3 = nq3; h3 = nh3;
        }
        a0.x = fmaf(q0, h0.x, a0.x);
        a0.y = fmaf(q0, h0.y, a0.y);
        a0.z = fmaf(q0, h0.z, a0.z);
        a0.w = fmaf(q0, h0.w, a0.w);
        a1.x = fmaf(q1, h1.x, a1.x);
        a1.y = fmaf(q1, h1.y, a1.y);
        a1.z = fmaf(q1, h1.z, a1.z);
        a1.w = fmaf(q1, h1.w, a1.w);
        a2.x = fmaf(q2, h2.x, a2.x);
        a2.y = fmaf(q2, h2.y, a2.y);
        a2.z = fmaf(q2, h2.z, a2.z);
        a2.w = fmaf(q2, h2.w, a2.w);
        a3.x = fmaf(q3, h3.x, a3.x);
        a3.y = fmaf(q3, h3.y, a3.y);
        a3.z = fmaf(q3, h3.z, a3.z);
        a3.w = fmaf(q3, h3.w, a3.w);
    }

    // within-half reductions (offsets < 32 never cross the half boundary)
#pragma unroll
    for (int off = 16; off > 0; off >>= 1) ssum += __shfl_xor(ssum, off, 64);
    a0.x = (a0.x + a1.x) + (a2.x + a3.x);
    a0.y = (a0.y + a1.y) + (a2.y + a3.y);
    a0.z = (a0.z + a1.z) + (a2.z + a3.z);
    a0.w = (a0.w + a1.w) + (a2.w + a3.w);
    a0.x += __shfl_xor(a0.x, 16, 64);  // combine sub 0/1
    a0.y += __shfl_xor(a0.y, 16, 64);
    a0.z += __shfl_xor(a0.z, 16, 64);
    a0.w += __shfl_xor(a0.w, 16, 64);

    if (sub == 0 && nok) {
        float inv = 1.f / (ssum + 1e-16f);
        const float4 bv = *reinterpret_cast<const float4*>(bias + f * 4);
        float4 o;
        o.x = fmaf(a0.x, inv, bv.x);
        o.y = fmaf(a0.y, inv, bv.y);
        o.z = fmaf(a0.z, inv, bv.z);
        o.w = fmaf(a0.w, inv, bv.w);
        float* dst = out + (size_t)node * out_stride + f * 4;
        if (do_relu) {
            o.x = fmaxf(o.x, 0.f);
            o.y = fmaxf(o.y, 0.f);
            o.z = fmaxf(o.z, 0.f);
            o.w = fmaxf(o.w, 0.f);
            *reinterpret_cast<float4*>(dst) = o;   // xbuf: re-read by next gemm
        } else {
            f32x4 o4 = {o.x, o.y, o.z, o.w};       // final out: never re-read
            __builtin_nontemporal_store(o4, reinterpret_cast<f32x4*>(dst));
        }
    }
}

extern "C" void kernel_launch(void* const* d_in, const int* in_sizes, int n_in,
                              void* d_out, int out_size, void* d_ws, size_t ws_size,
                              hipStream_t stream)
{
    (void)in_sizes; (void)n_in; (void)out_size;
    const float* x = (const float*)d_in[0];
    const float* edge_weight = (const float*)d_in[1];
    const float* W0 = (const float*)d_in[2];
    const float* W1 = (const float*)d_in[3];
    const float* W2 = (const float*)d_in[4];
    const float* a_src = (const float*)d_in[5];
    const float* a_dst = (const float*)d_in[6];
    const float* bias = (const float*)d_in[7];
    const int* edge_index = (const int*)d_in[8];
    float* out = (float*)d_out;

    char* ws = (char*)d_ws;
    size_t off = 0;
    auto alloc = [&](size_t bytes) {
        void* p = ws + off;
        off += (bytes + 255) & ~(size_t)255;
        return p;
    };
    int2* sedge = (int2*)alloc((size_t)R_REL * ETOT * 8);        // 39.6 MB
    int* bh = (int*)alloc((size_t)R_REL * NBLK * NBUCK * 4);     // 1.08 MB
    int* bhoff = (int*)alloc((size_t)R_REL * NBLK * NBUCK * 4);  // 1.08 MB
    int* btot = (int*)alloc((size_t)R_REL * NBUCK * 4);
    int* bbase = (int*)alloc((size_t)R_REL * (NBUCK + 1) * 4);
    int* rs = (int*)alloc((size_t)R_REL * (N_NODES + 1) * 4);

    // batched path needs 3x node buffers (~78 MB extra); fall back if ws too small
    size_t per_rel = ((size_t)N_NODES * 64 * 4 * 2 + (size_t)N_NODES * 4 * 2 + 1024);
    int K = (ws_size >= off + 3 * per_rel + (1 << 20)) ? 3 : 1;
    float* hbuf = (float*)alloc((size_t)K * N_NODES * 64 * 4);
    float* xbuf = (float*)alloc((size_t)K * N_NODES * 64 * 4);
    float* asv = (float*)alloc((size_t)K * N_NODES * 4);
    float* adv = (float*)alloc((size_t)K * N_NODES * 4);

    const int AGG_BLOCKS = (((N_NODES + 1) / 2) * 64 + 255) / 256;  // 6250 (2 nodes/wave)
    const int GEMM_BLOCKS = (N_NODES + 63) / 64;                    // 782
    const size_t HS = (size_t)N_NODES * 64;
    const size_t VS = (size_t)N_NODES;

    // batched CSR build for all 3 relations (5 launches, no global atomics)
    partA_hist<<<R_REL * NBLK, 256, 0, stream>>>(edge_index, bh);
    partA2_scan<<<R_REL * NBUCK, 256, 0, stream>>>(bh, bhoff, btot);
    partA3_scan<<<R_REL, 256, 0, stream>>>(btot, bbase);
    partB_scatter<<<R_REL * NBLK, 256, 0, stream>>>(edge_index, edge_weight,
                                                    bh, bhoff, bbase, sedge);
    partC_sort<<<R_REL * NBUCK, 256, 0, stream>>>(bbase, sedge, rs);

    if (K == 3) {
        // layer-lockstep: one gemm + one agg dispatch per layer, grid.y = 3 relations
        for (int i = 0; i < 3; ++i) {
            if (i == 0)
                gemm_alpha_kernel<D_IN><<<dim3(GEMM_BLOCKS, 3), 256, 0, stream>>>(
                    x, 0, W0, (size_t)D_IN * H_DIM,
                    a_src + i * H_DIM, a_dst + i * H_DIM, 3 * H_DIM,
                    hbuf, HS, asv, adv, VS, 0);
            else
                gemm_alpha_kernel<H_DIM><<<dim3(GEMM_BLOCKS, 3), 256, 0, stream>>>(
                    xbuf, HS, (i == 1 ? W1 : W2), (size_t)H_DIM * H_DIM,
                    a_src + i * H_DIM, a_dst + i * H_DIM, 3 * H_DIM,
                    hbuf, HS, asv, adv, VS, 0);
            if (i < 2)
                agg_kernel<<<dim3(AGG_BLOCKS, 3), 256, 0, stream>>>(
                    rs, sedge, asv, adv, VS, hbuf, HS,
                    bias + i * H_DIM, 3 * H_DIM,
                    xbuf, HS, 64, 1, 0);
            else
                agg_kernel<<<dim3(AGG_BLOCKS, 3), 256, 0, stream>>>(
                    rs, sedge, asv, adv, VS, hbuf, HS,
                    bias + i * H_DIM, 3 * H_DIM,
                    out, 64, 192, 0, 0);
        }
    } else {
        for (int r = 0; r < R_REL; ++r) {
            for (int i = 0; i < 3; ++i) {
                if (i == 0)
                    gemm_alpha_kernel<D_IN><<<dim3(GEMM_BLOCKS, 1), 256, 0, stream>>>(
                        x, 0, W0, (size_t)D_IN * H_DIM,
                        a_src + i * H_DIM, a_dst + i * H_DIM, 3 * H_DIM,
                        hbuf, 0, asv, adv, 0, r);
                else
                    gemm_alpha_kernel<H_DIM><<<dim3(GEMM_BLOCKS, 1), 256, 0, stream>>>(
                        xbuf, 0, (i == 1 ? W1 : W2), (size_t)H_DIM * H_DIM,
                        a_src + i * H_DIM, a_dst + i * H_DIM, 3 * H_DIM,
                        hbuf, 0, asv, adv, 0, r);
                if (i < 2)
                    agg_kernel<<<dim3(AGG_BLOCKS, 1), 256, 0, stream>>>(
                        rs, sedge, asv, adv, 0, hbuf, 0,
                        bias + i * H_DIM, 3 * H_DIM,
                        xbuf, 0, 64, 1, r);
                else
                    agg_kernel<<<dim3(AGG_BLOCKS, 1), 256, 0, stream>>>(
                        rs, sedge, asv, adv, 0, hbuf, 0,
                        bias + i * H_DIM, 3 * H_DIM,
                        out + r * 64, 0, 192, 0, r);
            }
        }
    }
}